// Round 3
// baseline (37.646 us; speedup 1.0000x reference)
//
#include <hip/hip_runtime.h>
#include <math.h>

// FNOGeoEncoder — exact algebraic reduction (only the DC mode survives the
// final mean):
//   S       = sum_t V[t,:]                          (3,)
//   X0[c]   = fc0_w[c,:].S + N*fc0_b[c]             (256,)
//   X_{k+1} = Re(sc_w[k,:,:,0])^T X_k               (4 matvecs 256x256)
//   feat    = X4 / N
//   z       = tanh(feat@fc1_w^T + fc1_b)@fc2_w^T + fc2_b
//
// Cost structure (measured r1/r2): the mandatory mode-0 gather (262144
// lines, one per 4 KB page across 1 GB) is DRAM-random-line bound at
// ~29 us; everything else is tail. This version shaves the tail:
//   K0 vsum -> K1 gather(+lift in spare block, transposed compact W)
//   -> K2..K5 matvec (256 blocks each, contiguous reads) -> K6 head.

constexpr int kN = 131072;
constexpr int kVsumBlocks = 384;     // 384*256 float4 = 98304 = 131072*3/4
constexpr int kGatherBlocks = 256;   // 256*256 threads * 4 layers = 262144
constexpr size_t kLayerStrideF = (size_t)256 * 256 * 512 * 2;  // 67108864 floats

// ws layout (floats):
constexpr size_t WS_WT   = 0;        // 262144: Wt[l][o][c] compact
constexpr size_t WS_PART = 262144;   // 1152:  vsum partials [384][3]
constexpr size_t WS_X    = 263296;   // 5*256: X0..X4

__global__ __launch_bounds__(256) void vsum(const float* __restrict__ V,
                                            float* __restrict__ ws) {
    int t = threadIdx.x, vb = blockIdx.x;
    int q = vb * 256 + t;  // float4 index
    const float4 v = reinterpret_cast<const float4*>(V)[q];
    int r = q % 3;  // component of first lane (f=4q, f%3 == q%3)
    float a[3] = {0.f, 0.f, 0.f};
    a[r] = v.x + v.w;
    a[(r + 1) % 3] = v.y;
    a[(r + 2) % 3] = v.z;
    __shared__ float sred[3][256];
    sred[0][t] = a[0]; sred[1][t] = a[1]; sred[2][t] = a[2];
    __syncthreads();
    for (int off = 128; off > 0; off >>= 1) {
        if (t < off) {
            sred[0][t] += sred[0][t + off];
            sred[1][t] += sred[1][t + off];
            sred[2][t] += sred[2][t + off];
        }
        __syncthreads();
    }
    if (t == 0) {
        float* partials = ws + WS_PART;
        partials[vb * 3 + 0] = sred[0][0];
        partials[vb * 3 + 1] = sred[1][0];
        partials[vb * 3 + 2] = sred[2][0];
    }
}

__global__ __launch_bounds__(256) void gather_lift(const float* __restrict__ sc_w,
                                                   const float* __restrict__ fc0_w,
                                                   const float* __restrict__ fc0_b,
                                                   float* __restrict__ ws) {
    int b = blockIdx.x, t = threadIdx.x;
    if (b < kGatherBlocks) {
        int rem = b * 256 + t;          // flat (c,o), o fastest
        int c = rem >> 8, o = rem & 255;
        const float* src = sc_w + (size_t)rem * 1024;  // 4096 B stride
        float w0 = src[0];
        float w1 = src[kLayerStrideF];
        float w2 = src[2 * kLayerStrideF];
        float w3 = src[3 * kLayerStrideF];
        size_t dst = (size_t)o * 256 + c;  // transposed: Wt[l][o][c]
        ws[dst]          = w0;
        ws[65536 + dst]  = w1;
        ws[131072 + dst] = w2;
        ws[196608 + dst] = w3;
    } else {
        // lift block: S-reduce (depends only on vsum kernel) + X0
        __shared__ float red[256];
        __shared__ float S[3];
        const float* part = ws + WS_PART;
        for (int j = 0; j < 3; ++j) {
            float a = part[t * 3 + j] + ((t < kVsumBlocks - 256) ? part[(t + 256) * 3 + j] : 0.f);
            red[t] = a;
            __syncthreads();
            for (int off = 128; off > 0; off >>= 1) {
                if (t < off) red[t] += red[t + off];
                __syncthreads();
            }
            if (t == 0) S[j] = red[0];
            __syncthreads();
        }
        ws[WS_X + t] = S[0] * fc0_w[t * 3] + S[1] * fc0_w[t * 3 + 1] +
                       S[2] * fc0_w[t * 3 + 2] + (float)kN * fc0_b[t];
    }
}

__global__ __launch_bounds__(256) void matvec_dc(const float* __restrict__ Wt,
                                                 const float* __restrict__ Xin,
                                                 float* __restrict__ Xout) {
    int o = blockIdx.x, t = threadIdx.x;
    __shared__ float red[256];
    red[t] = Wt[o * 256 + t] * Xin[t];  // contiguous 1 KB per block
    __syncthreads();
    for (int off = 128; off > 0; off >>= 1) {
        if (t < off) red[t] += red[t + off];
        __syncthreads();
    }
    if (t == 0) Xout[o] = red[0];
}

__global__ __launch_bounds__(256) void head(const float* __restrict__ X4,
                                            const float* __restrict__ fc1_w,
                                            const float* __restrict__ fc1_b,
                                            const float* __restrict__ fc2_w,
                                            const float* __restrict__ fc2_b,
                                            float* __restrict__ out) {
    __shared__ float feat[256];
    __shared__ float hred[256];
    __shared__ float h[128];
    int t = threadIdx.x;
    feat[t] = X4[t] * (1.0f / (float)kN);
    __syncthreads();
    {
        int j = t & 127, s = t >> 7;  // 128 outputs, split-K by 2
        float acc = 0.f;
        #pragma unroll 8
        for (int i = 0; i < 128; ++i) acc += feat[s * 128 + i] * fc1_w[j * 256 + s * 128 + i];
        hred[s * 128 + j] = acc;
        __syncthreads();
        if (t < 128) h[t] = tanhf(hred[t] + hred[128 + t] + fc1_b[t]);
        __syncthreads();
    }
    float acc = fc2_b[t];
    #pragma unroll 8
    for (int i = 0; i < 128; ++i) acc += h[i] * fc2_w[t * 128 + i];
    out[t] = acc;
}

extern "C" void kernel_launch(void* const* d_in, const int* in_sizes, int n_in,
                              void* d_out, int out_size, void* d_ws, size_t ws_size,
                              hipStream_t stream) {
    const float* V     = (const float*)d_in[0];
    const float* fc0_w = (const float*)d_in[1];
    const float* fc0_b = (const float*)d_in[2];
    const float* sc_w  = (const float*)d_in[3];
    const float* fc1_w = (const float*)d_in[4];
    const float* fc1_b = (const float*)d_in[5];
    const float* fc2_w = (const float*)d_in[6];
    const float* fc2_b = (const float*)d_in[7];
    float* out = (float*)d_out;
    float* ws = (float*)d_ws;

    vsum<<<kVsumBlocks, 256, 0, stream>>>(V, ws);
    gather_lift<<<kGatherBlocks + 1, 256, 0, stream>>>(sc_w, fc0_w, fc0_b, ws);

    float* X = ws + WS_X;
    for (int l = 0; l < 4; ++l) {
        matvec_dc<<<256, 256, 0, stream>>>(ws + (size_t)l * 65536, X + l * 256, X + (l + 1) * 256);
    }
    head<<<1, 256, 0, stream>>>(X + 4 * 256, fc1_w, fc1_b, fc2_w, fc2_b, out);
}